// Round 1
// baseline (2784.154 us; speedup 1.0000x reference)
//
#include <hip/hip_runtime.h>

typedef _Float16 half8 __attribute__((ext_vector_type(8)));
typedef float f32x4 __attribute__((ext_vector_type(4)));

// ---- ws layout (offsets in halves). All matrices have K=128 -> 4 k-chunks.
// frag layout: idx = (((nt*4 + kc)*64) + lane)*8 + j  ==  element index e itself.
constexpr int OFF_W0HI   = 0;        // 16384
constexpr int OFF_W0LO   = 16384;
constexpr int OFF_WL     = 32768;    // + m*32768 (hi), +16384 (lo), m=0..2
constexpr int OFF_WFHI   = 131072;   // 262144
constexpr int OFF_WFLO   = 393216;
constexpr int OFF_WLASTHI = 655360;  // 8192
constexpr int OFF_WLASTLO = 663552;  // total 671744 halves = 1.31 MB

__device__ __forceinline__ void cvt_elem(const float* __restrict__ W,
                                         _Float16* __restrict__ hi,
                                         _Float16* __restrict__ lo, int e) {
  int j  = e & 7;
  int l  = (e >> 3) & 63;
  int r  = e >> 9;
  int kc = r & 3;
  int nt = r >> 2;
  int row = nt * 16 + (l & 15);
  int col = kc * 32 + ((l >> 4) << 3) + j;
  float v = W[row * 128 + col];
  _Float16 h = (_Float16)v;
  hi[e] = h;
  lo[e] = (_Float16)(v - (float)h);
}

__global__ __launch_bounds__(256) void prep_kernel(const float* __restrict__ W0,
                                                   const float* __restrict__ Wl,
                                                   const float* __restrict__ Wf,
                                                   const float* __restrict__ Wlast,
                                                   _Float16* __restrict__ ws) {
  int e = blockIdx.x * 256 + threadIdx.x;
  if (e < 16384) {
    cvt_elem(W0, ws + OFF_W0HI, ws + OFF_W0LO, e);
  } else if (e < 65536) {
    int ee = e - 16384;
    int m = ee >> 14;          // which layer
    ee &= 16383;
    cvt_elem(Wl + m * 16384, ws + OFF_WL + m * 32768,
             ws + OFF_WL + m * 32768 + 16384, ee);
  } else if (e < 327680) {
    cvt_elem(Wf, ws + OFF_WFHI, ws + OFF_WFLO, e - 65536);
  } else if (e < 335872) {
    cvt_elem(Wlast, ws + OFF_WLASTHI, ws + OFF_WLASTLO, e - 327680);
  }
}

// 3-MFMA split tile: acc += Ahi*Bhi + Alo*Bhi + Ahi*Blo  (K=128, 4 chunks)
__device__ __forceinline__ f32x4 mm_tile3(const _Float16* __restrict__ A_hi,
                                          const _Float16* __restrict__ A_lo,
                                          const _Float16* __restrict__ Bhi,
                                          const _Float16* __restrict__ Blo,
                                          int row, int g) {
  f32x4 acc = {0.f, 0.f, 0.f, 0.f};
  const int lane = g * 16 + row;
#pragma unroll
  for (int kc = 0; kc < 4; ++kc) {
    half8 ah = *(const half8*)(A_hi + row * 136 + kc * 32 + g * 8);
    half8 al = *(const half8*)(A_lo + row * 136 + kc * 32 + g * 8);
    half8 bh = *(const half8*)(Bhi + (kc * 64 + lane) * 8);
    half8 bl = *(const half8*)(Blo + (kc * 64 + lane) * 8);
    acc = __builtin_amdgcn_mfma_f32_16x16x32_f16(ah, bh, acc, 0, 0, 0);
    acc = __builtin_amdgcn_mfma_f32_16x16x32_f16(al, bh, acc, 0, 0, 0);
    acc = __builtin_amdgcn_mfma_f32_16x16x32_f16(ah, bl, acc, 0, 0, 0);
  }
  return acc;
}

__device__ __forceinline__ void hidden_layer(const _Float16 (*srcHi)[136],
                                             const _Float16 (*srcLo)[136],
                                             _Float16 (*dstHi)[136],
                                             _Float16 (*dstLo)[136],
                                             const _Float16* __restrict__ wsHi,
                                             const _Float16* __restrict__ wsLo,
                                             const float* __restrict__ bias,
                                             int w, int row, int g) {
  f32x4 acc = mm_tile3(&srcHi[0][0], &srcLo[0][0], wsHi + w * 2048,
                       wsLo + w * 2048, row, g);
  int n = w * 16 + row;   // row here = col of C
  float bv = bias[n];
#pragma unroll
  for (int r = 0; r < 4; ++r) {
    float v = fmaxf(acc[r] + bv, 0.f);
    _Float16 h = (_Float16)v;
    dstHi[g * 4 + r][n] = h;
    dstLo[g * 4 + r][n] = (_Float16)(v - (float)h);
  }
}

__device__ __forceinline__ void out_gemm(int tt, int gb0, int w, int row, int g,
                                         const float (*zS)[128],
                                         const _Float16* __restrict__ ws,
                                         const float* __restrict__ b_last,
                                         float* __restrict__ out) {
  f32x4 acc = {0.f, 0.f, 0.f, 0.f};
  const int lane = g * 16 + row;
#pragma unroll
  for (int kc = 0; kc < 4; ++kc) {
    half8 ah, al;
#pragma unroll
    for (int j = 0; j < 8; ++j) {
      float v = zS[row][kc * 32 + g * 8 + j];
      _Float16 h = (_Float16)v;
      ah[j] = h;
      al[j] = (_Float16)(v - (float)h);
    }
    half8 bh = *(const half8*)(ws + OFF_WLASTHI + w * 2048 + (kc * 64 + lane) * 8);
    half8 bl = *(const half8*)(ws + OFF_WLASTLO + w * 2048 + (kc * 64 + lane) * 8);
    acc = __builtin_amdgcn_mfma_f32_16x16x32_f16(ah, bh, acc, 0, 0, 0);
    acc = __builtin_amdgcn_mfma_f32_16x16x32_f16(al, bh, acc, 0, 0, 0);
    acc = __builtin_amdgcn_mfma_f32_16x16x32_f16(ah, bl, acc, 0, 0, 0);
  }
  int o = w * 16 + row;
  float bv = b_last[o];
#pragma unroll
  for (int r = 0; r < 4; ++r) {
    int m = g * 4 + r;
    float x = acc[r] + bv;
    float sg = __fdividef(1.f, 1.f + __expf(-x));  // inf -> 0, 0 -> 1 : safe
    out[((size_t)(gb0 + m) * 32 + tt) * 64 + o] = sg;
  }
}

__global__ __launch_bounds__(512) void cde_kernel(
    const float* __restrict__ coeffs, const float* __restrict__ W_init,
    const float* __restrict__ b_init, const float* __restrict__ b0,
    const float* __restrict__ bl, const float* __restrict__ bf,
    const float* __restrict__ b_last, const _Float16* __restrict__ ws,
    float* __restrict__ out) {
  __shared__ float zS[16][128];
  __shared__ float kS[3][16][128];   // k1,k2,k3 (k4 fused into zS update)
  __shared__ float dxS[16][16];
  __shared__ _Float16 aHi[16][136], aLo[16][136];
  __shared__ _Float16 h0Hi[16][136], h0Lo[16][136];
  __shared__ _Float16 h1Hi[16][136], h1Lo[16][136];

  const int tid = threadIdx.x;
  const int w = tid >> 6;
  const int lane = tid & 63;
  const int row = lane & 15;  // batch row for A-frags; col for C-frags
  const int g = lane >> 4;
  const int gb0 = blockIdx.x * 16;

  // ---- z0 = x0 @ W_init^T + b_init  (fp32 VALU, tiny)
  for (int e = tid; e < 2048; e += 512) {
    int b = e >> 7, n = e & 127;
    const float* cr = coeffs + (size_t)(gb0 + b) * (31 * 64);  // t=0, 'a' block
    float s = b_init[n];
#pragma unroll
    for (int i = 0; i < 16; ++i) s += cr[i] * W_init[n * 16 + i];
    zS[b][n] = s;
  }
  __syncthreads();

  if (w < 4) out_gemm(0, gb0, w, row, g, zS, ws, b_last, out);

#pragma unroll 1
  for (int t = 0; t < 31; ++t) {
#pragma unroll 1
    for (int s = 0; s < 4; ++s) {
      // ---- dx + zz prep (and on s==3, fold partial z-update)
      if (tid < 256) {
        int b = tid >> 4, i = tid & 15;
        const float* cr = coeffs + ((size_t)(gb0 + b) * 31 + t) * 64;
        float frac = (s == 3) ? 1.f : s * (1.f / 3.f);
        dxS[b][i] = cr[16 + i] + (cr[32 + i] + cr[48 + i] * frac) * frac;
      }
      for (int e = tid; e < 2048; e += 512) {
        int b = e >> 7, kx = e & 127;
        float z = zS[b][kx];
        float v = z;
        if (s == 1) {
          v += (1.f / 3.f) * kS[0][b][kx];
        } else if (s == 2) {
          v += kS[1][b][kx] - (1.f / 3.f) * kS[0][b][kx];
        } else if (s == 3) {
          float k1 = kS[0][b][kx], k2 = kS[1][b][kx], k3 = kS[2][b][kx];
          v += k1 - k2 + k3;
          zS[b][kx] = z + 0.125f * (k1 + 3.f * (k2 + k3));  // + k4/8 added in G5
        }
        _Float16 h = (_Float16)v;
        aHi[b][kx] = h;
        aLo[b][kx] = (_Float16)(v - (float)h);
      }
      __syncthreads();

      // ---- G1..G4: MLP chain (each wave owns one 16-wide N-tile)
      hidden_layer(aHi, aLo, h0Hi, h0Lo, ws + OFF_W0HI, ws + OFF_W0LO, b0, w, row, g);
      __syncthreads();
      hidden_layer(h0Hi, h0Lo, h1Hi, h1Lo, ws + OFF_WL, ws + OFF_WL + 16384, bl, w, row, g);
      __syncthreads();
      hidden_layer(h1Hi, h1Lo, h0Hi, h0Lo, ws + OFF_WL + 32768, ws + OFF_WL + 32768 + 16384, bl + 128, w, row, g);
      __syncthreads();
      hidden_layer(h0Hi, h0Lo, h1Hi, h1Lo, ws + OFF_WL + 65536, ws + OFF_WL + 65536 + 16384, bl + 256, w, row, g);
      __syncthreads();

      // ---- G5: f = tanh(h @ Wf^T + bf), k = einsum(f, dx). 16 tiles/wave.
#pragma unroll 2
      for (int it = 0; it < 16; ++it) {
        int nt = w * 16 + it;  // = h index
        f32x4 acc = mm_tile3(&h1Hi[0][0], &h1Lo[0][0], ws + OFF_WFHI + nt * 2048,
                             ws + OFF_WFLO + nt * 2048, row, g);
        float bv = bf[nt * 16 + row];  // row = i (col of tile)
        float ts[4];
#pragma unroll
        for (int r = 0; r < 4; ++r) {
          float x = acc[r] + bv;
          x = fminf(fmaxf(x, -20.f), 20.f);
          float eh = __expf(2.f * x);
          float th = 1.f - __fdividef(2.f, eh + 1.f);  // tanh
          ts[r] = th * dxS[g * 4 + r][row];
        }
#pragma unroll
        for (int off = 1; off < 16; off <<= 1) {
#pragma unroll
          for (int r = 0; r < 4; ++r) ts[r] += __shfl_xor(ts[r], off);
        }
        if (row == 0) {
#pragma unroll
          for (int r = 0; r < 4; ++r) {
            if (s < 3) kS[s][g * 4 + r][nt] = ts[r];
            else       zS[g * 4 + r][nt] += 0.125f * ts[r];
          }
        }
      }
      __syncthreads();
    }
    if (w < 4) out_gemm(t + 1, gb0, w, row, g, zS, ws, b_last, out);
  }
}

extern "C" void kernel_launch(void* const* d_in, const int* in_sizes, int n_in,
                              void* d_out, int out_size, void* d_ws, size_t ws_size,
                              hipStream_t stream) {
  const float* coeffs = (const float*)d_in[1];
  const float* W_init = (const float*)d_in[2];
  const float* b_init = (const float*)d_in[3];
  const float* W0     = (const float*)d_in[4];
  const float* b0     = (const float*)d_in[5];
  const float* Wl     = (const float*)d_in[6];
  const float* bl     = (const float*)d_in[7];
  const float* Wf     = (const float*)d_in[8];
  const float* bf     = (const float*)d_in[9];
  const float* Wlast  = (const float*)d_in[10];
  const float* b_last = (const float*)d_in[11];
  _Float16* ws = (_Float16*)d_ws;
  float* out = (float*)d_out;

  prep_kernel<<<1312, 256, 0, stream>>>(W0, Wl, Wf, Wlast, ws);
  cde_kernel<<<16, 512, 0, stream>>>(coeffs, W_init, b_init, b0, bl, bf, b_last,
                                     ws, out);
}